// Round 1
// baseline (434.678 us; speedup 1.0000x reference)
//
#include <hip/hip_runtime.h>

// LIF activation: spikes[b,t,c] over a sequential T-scan.
// B*C = 65536 independent chains; memory-bound (524 MB HBM traffic, ~83us floor).

constexpr int B = 128;
constexpr int T = 1000;
constexpr int C = 512;
constexpr int UNROLL = 20;   // 1000 = 50 * 20; ping-pong prefetch depth

__global__ __launch_bounds__(256) void lif_kernel(
    const float* __restrict__ x, const float* __restrict__ w_leak,
    float* __restrict__ out) {
#pragma clang fp contract(off)
  const int g = blockIdx.x * blockDim.x + threadIdx.x;
  const int b = g >> 9;          // / C
  const int c = g & (C - 1);     // % C
  const float decay = 1.0f - w_leak[c];
  const size_t base = (size_t)b * T * C + c;
  const float* xp = x + base;
  float* op = out + base;

  float cur[UNROLL];
  float nxt[UNROLL];

  // preload batch 0
#pragma unroll
  for (int u = 0; u < UNROLL; ++u) cur[u] = xp[(size_t)u * C];

  float Vm = 0.0f;
  int t = 0;
  for (int it = 0; it < T / UNROLL - 1; ++it) {
    // prefetch next batch (independent of the Vm chain -> overlaps compute)
#pragma unroll
    for (int u = 0; u < UNROLL; ++u)
      nxt[u] = xp[(size_t)(t + UNROLL + u) * C];

    // compute current batch (serial Vm dependency)
#pragma unroll
    for (int u = 0; u < UNROLL; ++u) {
      float dv = decay * Vm;                 // one rounding (no FMA)
      dv = (Vm < 1.0f) ? dv : 0.0f;          // hard-reset gate (exact)
      float s = cur[u] + dv;                 // one rounding
      Vm = fmaxf(s, 0.0f);                   // relu
      op[(size_t)(t + u) * C] = (Vm > 1.0f) ? 1.0f : 0.0f;  // spike
    }

    // rotate buffers
#pragma unroll
    for (int u = 0; u < UNROLL; ++u) cur[u] = nxt[u];
    t += UNROLL;
  }

  // last batch (no prefetch)
#pragma unroll
  for (int u = 0; u < UNROLL; ++u) {
    float dv = decay * Vm;
    dv = (Vm < 1.0f) ? dv : 0.0f;
    float s = cur[u] + dv;
    Vm = fmaxf(s, 0.0f);
    op[(size_t)(t + u) * C] = (Vm > 1.0f) ? 1.0f : 0.0f;
  }
}

extern "C" void kernel_launch(void* const* d_in, const int* in_sizes, int n_in,
                              void* d_out, int out_size, void* d_ws, size_t ws_size,
                              hipStream_t stream) {
  const float* x = (const float*)d_in[0];
  const float* w = (const float*)d_in[1];
  float* out = (float*)d_out;
  dim3 block(256);
  dim3 grid((B * C) / 256);   // 256 blocks -> 1 per CU
  lif_kernel<<<grid, block, 0, stream>>>(x, w, out);
}

// Round 2
// 413.686 us; speedup vs baseline: 1.0507x; 1.0507x over previous
//
#include <hip/hip_runtime.h>

// LIF activation: spikes[b,t,c] over a sequential T-scan.
// B*C = 65536 chains (1 wave/SIMD) -> latency hiding must come from load ILP.
// True A/B double-buffer (no rotate) keeps 2x20 loads in flight per wave.

constexpr int B = 128;
constexpr int T = 1000;
constexpr int C = 512;
constexpr int U = 20;           // steps per batch
constexpr int NBATCH = T / U;   // 50

__global__ __launch_bounds__(256) void lif_kernel(
    const float* __restrict__ x, const float* __restrict__ w_leak,
    float* __restrict__ out) {
#pragma clang fp contract(off)
  const int g = blockIdx.x * blockDim.x + threadIdx.x;
  const int b = g >> 9;          // / C
  const int c = g & (C - 1);     // % C
  const float decay = 1.0f - w_leak[c];
  const size_t base = (size_t)b * T * C + c;
  const float* xp = x + base;
  float* op = out + base;

  float bufA[U], bufB[U];
  float Vm = 0.0f;

#define LOADB(buf, tb)                                                      \
  do {                                                                      \
    const float* p_ = xp + (size_t)(tb) * ((size_t)U * C);                  \
    _Pragma("unroll")                                                       \
    for (int u = 0; u < U; ++u)                                             \
      buf[u] = __builtin_nontemporal_load(p_ + (size_t)u * C);              \
  } while (0)

#define COMPUTE(buf, tb)                                                    \
  do {                                                                      \
    float* q_ = op + (size_t)(tb) * ((size_t)U * C);                        \
    _Pragma("unroll")                                                       \
    for (int u = 0; u < U; ++u) {                                           \
      float dv = decay * Vm;               /* one rounding, no FMA */       \
      dv = (Vm < 1.0f) ? dv : 0.0f;        /* hard-reset gate */            \
      float s = buf[u] + dv;               /* one rounding */               \
      Vm = fmaxf(s, 0.0f);                 /* relu */                       \
      __builtin_nontemporal_store((Vm > 1.0f) ? 1.0f : 0.0f,                \
                                  q_ + (size_t)u * C);                      \
    }                                                                       \
  } while (0)

  // Preload two batches: 40 loads in flight before first compute.
  LOADB(bufA, 0);
  LOADB(bufB, 1);

#pragma unroll 1
  for (int k = 0; k < NBATCH / 2 - 1; ++k) {   // 24 iterations
    COMPUTE(bufA, 2 * k);        // waits only on bufA's batch
    LOADB(bufA, 2 * k + 2);      // refill A; consumed next iteration
    COMPUTE(bufB, 2 * k + 1);
    LOADB(bufB, 2 * k + 3);
  }
  // Tail: batches 48, 49 already loaded.
  COMPUTE(bufA, NBATCH - 2);
  COMPUTE(bufB, NBATCH - 1);

#undef LOADB
#undef COMPUTE
}

extern "C" void kernel_launch(void* const* d_in, const int* in_sizes, int n_in,
                              void* d_out, int out_size, void* d_ws, size_t ws_size,
                              hipStream_t stream) {
  const float* x = (const float*)d_in[0];
  const float* w = (const float*)d_in[1];
  float* out = (float*)d_out;
  dim3 block(256);
  dim3 grid((B * C) / 256);   // 256 blocks -> 1 per CU
  lif_kernel<<<grid, block, 0, stream>>>(x, w, out);
}